// Round 4
// baseline (311.467 us; speedup 1.0000x reference)
//
#include <hip/hip_runtime.h>
#include <hip/hip_bf16.h>

#define BATCH 16
#define CIN   512
#define HW    3136
#define CM    512
#define CN    128
#define CBV   256

typedef short short8 __attribute__((ext_vector_type(8)));
typedef float f32x4  __attribute__((ext_vector_type(4)));

#define MFMA(a,b,c) __builtin_amdgcn_mfma_f32_16x16x32_bf16((a),(b),(c),0,0,0)

// convert 8 consecutive fp32 -> 8 bf16, store as one 16B chunk (LDS or global)
__device__ __forceinline__ void cvt_store8(__bf16* dst, const float* src) {
  const f32x4 a = *(const f32x4*)src;
  const f32x4 b = *(const f32x4*)(src + 4);
  __attribute__((aligned(16))) __bf16 t[8];
  t[0] = (__bf16)a[0]; t[1] = (__bf16)a[1]; t[2] = (__bf16)a[2]; t[3] = (__bf16)a[3];
  t[4] = (__bf16)b[0]; t[5] = (__bf16)b[1]; t[6] = (__bf16)b[2]; t[7] = (__bf16)b[3];
  *(uint4*)dst = *(uint4*)t;
}

// ---------------------------------------------------------------------------
// Kernel 0a: cast weights fp32->bf16 into Wbf = [wB 128x512 | wV 128x512 | wA 512x512]
// ---------------------------------------------------------------------------
__global__ __launch_bounds__(256) void wcast_kernel(
    const float* __restrict__ wB, const float* __restrict__ wV,
    const float* __restrict__ wA, __bf16* __restrict__ Wbf)
{
  size_t i = (size_t)blockIdx.x*2048 + (size_t)threadIdx.x*8;
  const float* src; size_t off;
  if (i < 65536)       { src = wB; off = i; }
  else if (i < 131072) { src = wV; off = i - 65536; }
  else                 { src = wA; off = i - 131072; }
  cvt_store8(Wbf + i, src + off);
}

// ---------------------------------------------------------------------------
// Kernel 0b: x[b][c][s] fp32 -> xT[b][s][c] bf16 (LDS transpose) AND xbf[b][c][s] bf16
// tile 128c x 64s per block
// ---------------------------------------------------------------------------
__global__ __launch_bounds__(256) void transpose_x_kernel(
    const float* __restrict__ x, __bf16* __restrict__ xT, __bf16* __restrict__ xbf)
{
  const int s0 = blockIdx.x * 64;
  const int c0 = blockIdx.y * 128;
  const int b  = blockIdx.z;
  const int tid = threadIdx.x;
  __shared__ __attribute__((aligned(16))) __bf16 T[64*136]; // [s][c]

  const float* xsrc = x + ((size_t)b*CIN + c0)*HW + s0;
  __bf16* xdst      = xbf + ((size_t)b*CIN + c0)*HW + s0;
  const int colg = tid & 7, row0 = tid >> 3;   // 8 s-octets x 32 c-rows
  #pragma unroll
  for (int p = 0; p < 4; ++p) {
    int c = row0 + 32*p;
    const float* sp = xsrc + (size_t)c*HW + colg*8;
    f32x4 v0 = *(const f32x4*)sp;
    f32x4 v1 = *(const f32x4*)(sp + 4);
    __attribute__((aligned(16))) __bf16 t[8];
    t[0]=(__bf16)v0[0]; t[1]=(__bf16)v0[1]; t[2]=(__bf16)v0[2]; t[3]=(__bf16)v0[3];
    t[4]=(__bf16)v1[0]; t[5]=(__bf16)v1[1]; t[6]=(__bf16)v1[2]; t[7]=(__bf16)v1[3];
    *(uint4*)(xdst + (size_t)c*HW + colg*8) = *(uint4*)t;
    #pragma unroll
    for (int j = 0; j < 8; ++j) T[(colg*8 + j)*136 + c] = t[j];
  }
  __syncthreads();
  __bf16* dst = xT + ((size_t)b*HW + s0)*CIN + c0;
  const int cg = tid & 15, sr = tid >> 4;
  #pragma unroll
  for (int p = 0; p < 4; ++p) {
    int srow = sr + 16*p;
    *(uint4*)&dst[(size_t)srow*CIN + cg*8] = *(uint4*)&T[srow*136 + cg*8];
  }
}

// ---------------------------------------------------------------------------
// Kernel 1: conv (wB|wV) @ x + bias with FUSED V-softmax.
//   writes BVB[b][n][s] (raw B-half, n<128, bf16)
//   writes attVT[b][s][n] (softmaxed V-half, transposed, bf16)
// block: 64 s-cols, all 256 channels. waves 0,1 = B half; waves 2,3 = V half.
// ---------------------------------------------------------------------------
__global__ __launch_bounds__(256) void conv_bv_kernel(
    const __bf16* __restrict__ Wbf, const __bf16* __restrict__ xT,
    const float* __restrict__ bB, const float* __restrict__ bV,
    __bf16* __restrict__ BVB, __bf16* __restrict__ attVT)
{
  const int s0  = blockIdx.x * 64;
  const int b   = blockIdx.y;
  const int tid = threadIdx.x;
  const int lane = tid & 63, w = tid >> 6;
  const int l15  = lane & 15, q = lane >> 4;

  __shared__ __attribute__((aligned(16))) char smem[46080]; // Wt 36864 | Xt 9216; aliased by T
  __bf16* Wt = (__bf16*)smem;            // [256][72]
  __bf16* Xt = (__bf16*)(smem + 36864);  // [64][72]
  __bf16* T  = (__bf16*)smem;            // [64][136] (epilogue, aliases Wt)
  __shared__ float Vm[2][64];
  __shared__ float Vs[2][64];

  f32x4 acc[4][4] = {};
  const __bf16* xTb = xT + (size_t)b*HW*CIN;
  const int colg = tid & 7, row0 = tid >> 3;

  for (int k0 = 0; k0 < CIN; k0 += 64) {
    #pragma unroll
    for (int p = 0; p < 8; ++p) {
      int row = row0 + 32*p;
      *(uint4*)&Wt[row*72 + colg*8] = *(const uint4*)(Wbf + (size_t)row*CIN + k0 + colg*8);
    }
    #pragma unroll
    for (int p = 0; p < 2; ++p) {
      int row = row0 + 32*p;
      *(uint4*)&Xt[row*72 + colg*8] = *(const uint4*)(xTb + (size_t)(s0+row)*CIN + k0 + colg*8);
    }
    __syncthreads();
    #pragma unroll
    for (int kk = 0; kk < 2; ++kk) {
      short8 a[4], bb[4];
      #pragma unroll
      for (int mi = 0; mi < 4; ++mi)
        a[mi] = *(short8*)&Wt[(w*64 + mi*16 + l15)*72 + kk*32 + q*8];
      #pragma unroll
      for (int si = 0; si < 4; ++si)
        bb[si] = *(short8*)&Xt[(si*16 + l15)*72 + kk*32 + q*8];
      #pragma unroll
      for (int mi = 0; mi < 4; ++mi)
        #pragma unroll
        for (int si = 0; si < 4; ++si)
          acc[mi][si] = MFMA(a[mi], bb[si], acc[mi][si]);
    }
    __syncthreads();
  }
  // after this barrier Wt/Xt are dead -> T may alias them.

  // per-lane bias for its 16 channels (mi, r): nch = w*64 + mi*16 + q*4 + r
  float bias[4][4];
  #pragma unroll
  for (int mi = 0; mi < 4; ++mi)
    #pragma unroll
    for (int r = 0; r < 4; ++r) {
      int nch = w*64 + mi*16 + q*4 + r;
      bias[mi][r] = (nch < CN) ? bB[nch] : bV[nch - CN];
    }

  if (w < 2) {
    // B half: write raw (bias added) bf16 rows
    const size_t outb = (size_t)b * CN * HW;
    #pragma unroll
    for (int mi = 0; mi < 4; ++mi)
      #pragma unroll
      for (int si = 0; si < 4; ++si) {
        int s = s0 + si*16 + l15;
        #pragma unroll
        for (int r = 0; r < 4; ++r) {
          int nch = w*64 + mi*16 + q*4 + r;
          BVB[outb + (size_t)nch*HW + s] = (__bf16)(acc[mi][si][r] + bias[mi][r]);
        }
      }
  } else {
    // V half: per-s max over the 128 V channels
    #pragma unroll
    for (int si = 0; si < 4; ++si) {
      float m = -1e30f;
      #pragma unroll
      for (int mi = 0; mi < 4; ++mi)
        #pragma unroll
        for (int r = 0; r < 4; ++r)
          m = fmaxf(m, acc[mi][si][r] + bias[mi][r]);
      m = fmaxf(m, __shfl_xor(m, 16));
      m = fmaxf(m, __shfl_xor(m, 32));
      if (q == 0) Vm[w-2][si*16 + l15] = m;
    }
  }
  __syncthreads();
  if (w >= 2) {
    #pragma unroll
    for (int si = 0; si < 4; ++si) {
      int idx = si*16 + l15;
      float ms = fmaxf(Vm[0][idx], Vm[1][idx]);
      float ssum = 0.f;
      #pragma unroll
      for (int mi = 0; mi < 4; ++mi)
        #pragma unroll
        for (int r = 0; r < 4; ++r) {
          float e = __expf(acc[mi][si][r] + bias[mi][r] - ms);
          acc[mi][si][r] = e;
          ssum += e;
        }
      ssum += __shfl_xor(ssum, 16);
      ssum += __shfl_xor(ssum, 32);
      if (q == 0) Vs[w-2][idx] = ssum;
    }
  }
  __syncthreads();
  if (w >= 2) {
    #pragma unroll
    for (int si = 0; si < 4; ++si) {
      int idx = si*16 + l15;
      float inv = 1.0f / (Vs[0][idx] + Vs[1][idx]);
      #pragma unroll
      for (int mi = 0; mi < 4; ++mi)
        #pragma unroll
        for (int r = 0; r < 4; ++r) {
          int j = (w-2)*64 + mi*16 + q*4 + r;
          T[idx*136 + j] = (__bf16)(acc[mi][si][r] * inv);
        }
    }
  }
  __syncthreads();
  // cooperative store T (64 s-rows x 128 n) -> attVT[b][s0+row][:]
  __bf16* dst = attVT + ((size_t)b*HW + s0)*CN;
  #pragma unroll
  for (int k = 0; k < 4; ++k) {
    int chunk = tid + 256*k;          // 1024 uint4 chunks
    int row = chunk >> 4, oct = chunk & 15;
    *(uint4*)&dst[(size_t)row*CN + oct*8] = *(uint4*)&T[row*136 + oct*8];
  }
}

// ---------------------------------------------------------------------------
// Kernel 2: per-(b,n) row stats of BVB: max and 1/sum(exp(v-max)).  2048 rows.
// one wave per row (4 rows per block).
// ---------------------------------------------------------------------------
__global__ __launch_bounds__(256) void bstats_kernel(
    const __bf16* __restrict__ BVB, float* __restrict__ sm, float* __restrict__ sinv)
{
  const int row = blockIdx.x*4 + (threadIdx.x >> 6);
  const int lane = threadIdx.x & 63;
  const __bf16* rp = BVB + (size_t)row*HW;

  uint4 raw[7];
  float mx = -1e30f;
  #pragma unroll
  for (int i = 0; i < 6; ++i) {
    raw[i] = *(const uint4*)(rp + (lane + 64*i)*8);
    const __bf16* v = (const __bf16*)&raw[i];
    #pragma unroll
    for (int j = 0; j < 8; ++j) mx = fmaxf(mx, (float)v[j]);
  }
  if (lane < 8) {
    raw[6] = *(const uint4*)(rp + (lane + 384)*8);
    const __bf16* v = (const __bf16*)&raw[6];
    #pragma unroll
    for (int j = 0; j < 8; ++j) mx = fmaxf(mx, (float)v[j]);
  }
  #pragma unroll
  for (int off = 1; off < 64; off <<= 1) mx = fmaxf(mx, __shfl_xor(mx, off));

  float sum = 0.f;
  #pragma unroll
  for (int i = 0; i < 6; ++i) {
    const __bf16* v = (const __bf16*)&raw[i];
    #pragma unroll
    for (int j = 0; j < 8; ++j) sum += __expf((float)v[j] - mx);
  }
  if (lane < 8) {
    const __bf16* v = (const __bf16*)&raw[6];
    #pragma unroll
    for (int j = 0; j < 8; ++j) sum += __expf((float)v[j] - mx);
  }
  #pragma unroll
  for (int off = 1; off < 64; off <<= 1) sum += __shfl_xor(sum, off);

  if (lane == 0) { sm[row] = mx; sinv[row] = 1.0f / sum; }
}

// ---------------------------------------------------------------------------
// Kernel 3: H[b][c][n] += sum_s xbf[b][c][s] * softmaxB(BVB)[n][s]
// tile 128c x 128n, split-K=7, exp applied at staging, fp32 atomics
// ---------------------------------------------------------------------------
__global__ __launch_bounds__(256) void h_gemm_kernel(
    const __bf16* __restrict__ xbf, const __bf16* __restrict__ BVB,
    const float* __restrict__ sm, const float* __restrict__ sinv,
    float* __restrict__ H)
{
  const int c0 = blockIdx.x * 128, b = blockIdx.y, kc = blockIdx.z;
  const int tid = threadIdx.x, lane = tid & 63, w = tid >> 6;
  const int l15 = lane & 15, q = lane >> 4;

  __shared__ __attribute__((aligned(16))) __bf16 At[128*72];  // x tile [c][s]
  __shared__ __attribute__((aligned(16))) __bf16 Bt[128*72];  // attB tile [n][s]
  f32x4 acc[8][2] = {};

  const __bf16* xb = xbf + ((size_t)b*CIN + c0)*HW;
  const __bf16* ab = BVB + (size_t)b*CN*HW;
  const float* smb = sm + b*CN;
  const float* sib = sinv + b*CN;
  const int colg = tid & 7, row0 = tid >> 3;

  for (int ki = 0; ki < 7; ++ki) {
    int k0 = kc*448 + ki*64;
    #pragma unroll
    for (int p = 0; p < 4; ++p) {
      int row = row0 + 32*p;
      *(uint4*)&At[row*72 + colg*8] = *(const uint4*)(xb + (size_t)row*HW + k0 + colg*8);
    }
    #pragma unroll
    for (int p = 0; p < 4; ++p) {
      int row = row0 + 32*p;
      uint4 rawv = *(const uint4*)(ab + (size_t)row*HW + k0 + colg*8);
      const __bf16* v = (const __bf16*)&rawv;
      float mrow = smb[row], irow = sib[row];
      __attribute__((aligned(16))) __bf16 t[8];
      #pragma unroll
      for (int j = 0; j < 8; ++j)
        t[j] = (__bf16)(__expf((float)v[j] - mrow) * irow);
      *(uint4*)&Bt[row*72 + colg*8] = *(uint4*)t;
    }
    __syncthreads();
    #pragma unroll
    for (int kk = 0; kk < 2; ++kk) {
      short8 a[8], bb[2];
      #pragma unroll
      for (int mi = 0; mi < 8; ++mi)
        a[mi] = *(short8*)&At[(mi*16 + l15)*72 + kk*32 + q*8];
      #pragma unroll
      for (int ni = 0; ni < 2; ++ni)
        bb[ni] = *(short8*)&Bt[(w*32 + ni*16 + l15)*72 + kk*32 + q*8];
      #pragma unroll
      for (int mi = 0; mi < 8; ++mi)
        #pragma unroll
        for (int ni = 0; ni < 2; ++ni)
          acc[mi][ni] = MFMA(a[mi], bb[ni], acc[mi][ni]);
    }
    __syncthreads();
  }

  float* Hb = H + (size_t)b*CIN*CN;
  #pragma unroll
  for (int mi = 0; mi < 8; ++mi)
    #pragma unroll
    for (int ni = 0; ni < 2; ++ni)
      #pragma unroll
      for (int r = 0; r < 4; ++r) {
        int c = c0 + mi*16 + q*4 + r;
        int n = w*32 + ni*16 + l15;
        atomicAdd(&Hb[c*CN + n], acc[mi][ni][r]);
      }
}

// ---------------------------------------------------------------------------
// Kernel 4: G[b] = wA @ H[b] + bA  (M=512 in 64-tiles, N=128, K=512) -> bf16
// ---------------------------------------------------------------------------
__global__ __launch_bounds__(256) void g_gemm_kernel(
    const __bf16* __restrict__ wAbf, const float* __restrict__ bA,
    const float* __restrict__ H, __bf16* __restrict__ G)
{
  const int m0 = blockIdx.x * 64, b = blockIdx.y;
  const int tid = threadIdx.x, lane = tid & 63, w = tid >> 6;
  const int l15 = lane & 15, q = lane >> 4;

  __shared__ __attribute__((aligned(16))) __bf16 At[64*72];
  __shared__ __attribute__((aligned(16))) __bf16 Bt[128*72];
  f32x4 acc[4][2] = {};

  const float* Hb = H + (size_t)b*CIN*CN;
  const int colg = tid & 7, row0 = tid >> 3;
  const int nn = tid & 127, gh = tid >> 7;

  for (int k0 = 0; k0 < CIN; k0 += 64) {
    #pragma unroll
    for (int p = 0; p < 2; ++p) {
      int row = row0 + 32*p;
      *(uint4*)&At[row*72 + colg*8] = *(const uint4*)(wAbf + (size_t)(m0+row)*CIN + k0 + colg*8);
    }
    #pragma unroll
    for (int p = 0; p < 4; ++p) {
      int g = gh + 2*p;
      __attribute__((aligned(16))) __bf16 tmp[8];
      #pragma unroll
      for (int j = 0; j < 8; ++j)
        tmp[j] = (__bf16)Hb[(size_t)(k0 + g*8 + j)*CN + nn];
      *(uint4*)&Bt[nn*72 + g*8] = *(uint4*)tmp;
    }
    __syncthreads();
    #pragma unroll
    for (int kk = 0; kk < 2; ++kk) {
      short8 a[4], bb[2];
      #pragma unroll
      for (int mi = 0; mi < 4; ++mi)
        a[mi] = *(short8*)&At[(mi*16 + l15)*72 + kk*32 + q*8];
      #pragma unroll
      for (int ni = 0; ni < 2; ++ni)
        bb[ni] = *(short8*)&Bt[(w*32 + ni*16 + l15)*72 + kk*32 + q*8];
      #pragma unroll
      for (int mi = 0; mi < 4; ++mi)
        #pragma unroll
        for (int ni = 0; ni < 2; ++ni)
          acc[mi][ni] = MFMA(a[mi], bb[ni], acc[mi][ni]);
    }
    __syncthreads();
  }

  #pragma unroll
  for (int mi = 0; mi < 4; ++mi)
    #pragma unroll
    for (int ni = 0; ni < 2; ++ni)
      #pragma unroll
      for (int r = 0; r < 4; ++r) {
        int m = m0 + mi*16 + q*4 + r;
        int n = w*32 + ni*16 + l15;
        G[((size_t)b*CM + m)*CN + n] = (__bf16)(acc[mi][ni][r] + bA[m]);
      }
}

// ---------------------------------------------------------------------------
// Kernel 5: Z[b][m][s] = sum_n G[b][m][n] * attVT[b][s][n]  -> fp32 output
// ---------------------------------------------------------------------------
__global__ __launch_bounds__(256) void z_gemm_kernel(
    const __bf16* __restrict__ G, const __bf16* __restrict__ attVT,
    float* __restrict__ out)
{
  const int m0 = blockIdx.x * 128, s0 = blockIdx.y * 64, b = blockIdx.z;
  const int tid = threadIdx.x, lane = tid & 63, w = tid >> 6;
  const int l15 = lane & 15, q = lane >> 4;

  __shared__ __attribute__((aligned(16))) __bf16 At[128*136];
  __shared__ __attribute__((aligned(16))) __bf16 Bt[64*136];

  const __bf16* Gb = G + ((size_t)b*CM + m0)*CN;
  const __bf16* Vb = attVT + ((size_t)b*HW + s0)*CN;
  const int g = tid & 15, r0 = tid >> 4;
  #pragma unroll
  for (int p = 0; p < 8; ++p) {
    int row = r0 + 16*p;
    *(uint4*)&At[row*136 + g*8] = *(const uint4*)(Gb + (size_t)row*CN + g*8);
  }
  #pragma unroll
  for (int p = 0; p < 4; ++p) {
    int row = r0 + 16*p;
    *(uint4*)&Bt[row*136 + g*8] = *(const uint4*)(Vb + (size_t)row*CN + g*8);
  }
  __syncthreads();

  f32x4 acc[8] = {};
  #pragma unroll
  for (int kk = 0; kk < 4; ++kk) {
    short8 bb = *(short8*)&Bt[(w*16 + l15)*136 + kk*32 + q*8];
    #pragma unroll
    for (int mi = 0; mi < 8; ++mi) {
      short8 a = *(short8*)&At[(mi*16 + l15)*136 + kk*32 + q*8];
      acc[mi] = MFMA(a, bb, acc[mi]);
    }
  }

  const int s = s0 + w*16 + l15;
  #pragma unroll
  for (int mi = 0; mi < 8; ++mi)
    #pragma unroll
    for (int r = 0; r < 4; ++r) {
      int m = m0 + mi*16 + q*4 + r;
      out[((size_t)b*CM + m)*HW + s] = acc[mi][r];
    }
}

// ======================= fallback-path kernels (R2-proven) ==================
__global__ __launch_bounds__(256) void conv_bv_gather_kernel(
    const float* __restrict__ x,
    const float* __restrict__ wB, const float* __restrict__ bB,
    const float* __restrict__ wV, const float* __restrict__ bV,
    __bf16* __restrict__ BV)
{
  const int s0  = blockIdx.x * 64;
  const int b   = blockIdx.y;
  const int tid = threadIdx.x;
  const int lane = tid & 63, w = tid >> 6;
  const int l15  = lane & 15, q = lane >> 4;

  __shared__ __attribute__((aligned(16))) __bf16 Wt[256*72];
  __shared__ __attribute__((aligned(16))) __bf16 Xt[64*72];

  f32x4 acc[4][4] = {};
  const float* xb = x + (size_t)b * CIN * HW;
  const int colg = tid & 7, row0 = tid >> 3;
  const int s_l = tid & 63, cb = tid >> 6;

  for (int k0 = 0; k0 < CIN; k0 += 64) {
    #pragma unroll
    for (int p = 0; p < 8; ++p) {
      int row = row0 + 32*p;
      const float* src = (row < 128) ? (wB + row*512) : (wV + (row-128)*512);
      cvt_store8(&Wt[row*72 + colg*8], src + k0 + colg*8);
    }
    #pragma unroll
    for (int p = 0; p < 2; ++p) {
      int cg = cb + 4*p;
      __attribute__((aligned(16))) __bf16 tmp[8];
      #pragma unroll
      for (int j = 0; j < 8; ++j)
        tmp[j] = (__bf16)xb[(size_t)(k0 + cg*8 + j)*HW + s0 + s_l];
      *(uint4*)&Xt[s_l*72 + cg*8] = *(uint4*)tmp;
    }
    __syncthreads();
    #pragma unroll
    for (int kk = 0; kk < 2; ++kk) {
      short8 a[4], bb[4];
      #pragma unroll
      for (int mi = 0; mi < 4; ++mi)
        a[mi] = *(short8*)&Wt[(w*64 + mi*16 + l15)*72 + kk*32 + q*8];
      #pragma unroll
      for (int si = 0; si < 4; ++si)
        bb[si] = *(short8*)&Xt[(si*16 + l15)*72 + kk*32 + q*8];
      #pragma unroll
      for (int mi = 0; mi < 4; ++mi)
        #pragma unroll
        for (int si = 0; si < 4; ++si)
          acc[mi][si] = MFMA(a[mi], bb[si], acc[mi][si]);
    }
    __syncthreads();
  }

  const size_t outb = (size_t)b * CBV * HW;
  #pragma unroll
  for (int mi = 0; mi < 4; ++mi)
    #pragma unroll
    for (int si = 0; si < 4; ++si) {
      int s = s0 + si*16 + l15;
      #pragma unroll
      for (int r = 0; r < 4; ++r) {
        int nch = w*64 + mi*16 + q*4 + r;
        float bias = (nch < CN) ? bB[nch] : bV[nch-CN];
        BV[outb + (size_t)nch*HW + s] = (__bf16)(acc[mi][si][r] + bias);
      }
    }
}

__global__ __launch_bounds__(256) void softmax_b_kernel(__bf16* __restrict__ BV)
{
  const int n = blockIdx.x, b = blockIdx.y;
  __bf16* row = BV + ((size_t)b*CBV + n)*HW;
  const int tid = threadIdx.x;

  float v[13];
  float mx = -1e30f;
  #pragma unroll
  for (int i = 0; i < 13; ++i) {
    int idx = tid + i*256;
    v[i] = (idx < HW) ? (float)row[idx] : -1e30f;
    mx = fmaxf(mx, v[i]);
  }
  #pragma unroll
  for (int off = 32; off > 0; off >>= 1) mx = fmaxf(mx, __shfl_down(mx, off));
  __shared__ float redm[4], reds[4];
  if ((tid & 63) == 0) redm[tid >> 6] = mx;
  __syncthreads();
  float m = fmaxf(fmaxf(redm[0], redm[1]), fmaxf(redm[2], redm[3]));

  float sum = 0.f;
  #pragma unroll
  for (int i = 0; i < 13; ++i) { v[i] = __expf(v[i] - m); sum += v[i]; }
  #pragma unroll
  for (int off = 32; off > 0; off >>= 1) sum += __shfl_down(sum, off);
  if ((tid & 63) == 0) reds[tid >> 6] = sum;
  __syncthreads();
  float inv = 1.0f / (reds[0] + reds[1] + reds[2] + reds[3]);

  #pragma unroll
  for (int i = 0; i < 13; ++i) {
    int idx = tid + i*256;
    if (idx < HW) row[idx] = (__bf16)(v[i] * inv);
  }
}

__global__ __launch_bounds__(256) void softmax_v_t_kernel(
    const __bf16* __restrict__ BV, __bf16* __restrict__ attVT)
{
  const int s0 = blockIdx.x * 64, b = blockIdx.y;
  const int tid = threadIdx.x;
  const int s_l = tid & 63, jg = tid >> 6;
  const __bf16* vb = BV + ((size_t)b*CBV + CN)*HW + s0 + s_l;

  float v[32];
  float mx = -1e30f;
  #pragma unroll
  for (int i = 0; i < 32; ++i) {
    v[i] = (float)vb[(size_t)(jg*32 + i)*HW];
    mx = fmaxf(mx, v[i]);
  }
  __shared__ float red[4][64];
  red[jg][s_l] = mx;
  __syncthreads();
  float m = fmaxf(fmaxf(red[0][s_l], red[1][s_l]), fmaxf(red[2][s_l], red[3][s_l]));
  float sum = 0.f;
  #pragma unroll
  for (int i = 0; i < 32; ++i) { v[i] = __expf(v[i] - m); sum += v[i]; }
  __syncthreads();
  red[jg][s_l] = sum;
  __syncthreads();
  float inv = 1.0f / (red[0][s_l] + red[1][s_l] + red[2][s_l] + red[3][s_l]);

  __shared__ __attribute__((aligned(16))) __bf16 T[64*136];
  #pragma unroll
  for (int u = 0; u < 4; ++u) {
    __attribute__((aligned(16))) __bf16 tmp[8];
    #pragma unroll
    for (int j = 0; j < 8; ++j) tmp[j] = (__bf16)(v[u*8 + j] * inv);
    *(uint4*)&T[s_l*136 + jg*32 + u*8] = *(uint4*)tmp;
  }
  __syncthreads();
  __bf16* dst = attVT + ((size_t)b*HW + s0)*CN;
  const int g = tid & 15, r0 = tid >> 4;
  #pragma unroll
  for (int p = 0; p < 4; ++p) {
    int row = r0 + 16*p;
    *(uint4*)&dst[row*CN + g*8] = *(uint4*)&T[row*136 + g*8];
  }
}

__global__ __launch_bounds__(256) void h_gemm_f32_kernel(
    const float* __restrict__ x, const __bf16* __restrict__ attB,
    float* __restrict__ H)
{
  const int c0 = blockIdx.x * 64, b = blockIdx.y, kc = blockIdx.z;
  const int tid = threadIdx.x, lane = tid & 63, w = tid >> 6;
  const int l15 = lane & 15, q = lane >> 4;

  __shared__ __attribute__((aligned(16))) __bf16 At[64*72];
  __shared__ __attribute__((aligned(16))) __bf16 Bt[128*72];
  f32x4 acc[4][2] = {};

  const float* xb = x + ((size_t)b*CIN + c0)*HW;
  const __bf16* ab = attB + (size_t)b*CBV*HW;
  const int colg = tid & 7, row0 = tid >> 3;

  for (int ki = 0; ki < 7; ++ki) {
    int k0 = kc*448 + ki*64;
    #pragma unroll
    for (int p = 0; p < 2; ++p) {
      int row = row0 + 32*p;
      cvt_store8(&At[row*72 + colg*8], xb + (size_t)row*HW + k0 + colg*8);
    }
    #pragma unroll
    for (int p = 0; p < 4; ++p) {
      int row = row0 + 32*p;
      *(uint4*)&Bt[row*72 + colg*8] = *(const uint4*)(ab + (size_t)row*HW + k0 + colg*8);
    }
    __syncthreads();
    #pragma unroll
    for (int kk = 0; kk < 2; ++kk) {
      short8 a[4], bb[2];
      #pragma unroll
      for (int mi = 0; mi < 4; ++mi)
        a[mi] = *(short8*)&At[(mi*16 + l15)*72 + kk*32 + q*8];
      #pragma unroll
      for (int ni = 0; ni < 2; ++ni)
        bb[ni] = *(short8*)&Bt[(w*32 + ni*16 + l15)*72 + kk*32 + q*8];
      #pragma unroll
      for (int mi = 0; mi < 4; ++mi)
        #pragma unroll
        for (int ni = 0; ni < 2; ++ni)
          acc[mi][ni] = MFMA(a[mi], bb[ni], acc[mi][ni]);
    }
    __syncthreads();
  }

  float* Hb = H + (size_t)b*CIN*CN;
  #pragma unroll
  for (int mi = 0; mi < 4; ++mi)
    #pragma unroll
    for (int ni = 0; ni < 2; ++ni)
      #pragma unroll
      for (int r = 0; r < 4; ++r) {
        int c = c0 + mi*16 + q*4 + r;
        int n = w*32 + ni*16 + l15;
        atomicAdd(&Hb[c*CN + n], acc[mi][ni][r]);
      }
}

__global__ __launch_bounds__(256) void g_gemm_f32w_kernel(
    const float* __restrict__ wA, const float* __restrict__ bA,
    const float* __restrict__ H, __bf16* __restrict__ G)
{
  const int m0 = blockIdx.x * 64, b = blockIdx.y;
  const int tid = threadIdx.x, lane = tid & 63, w = tid >> 6;
  const int l15 = lane & 15, q = lane >> 4;

  __shared__ __attribute__((aligned(16))) __bf16 At[64*72];
  __shared__ __attribute__((aligned(16))) __bf16 Bt[128*72];
  f32x4 acc[4][2] = {};

  const float* Hb = H + (size_t)b*CIN*CN;
  const int colg = tid & 7, row0 = tid >> 3;
  const int nn = tid & 127, gh = tid >> 7;

  for (int k0 = 0; k0 < CIN; k0 += 64) {
    #pragma unroll
    for (int p = 0; p < 2; ++p) {
      int row = row0 + 32*p;
      cvt_store8(&At[row*72 + colg*8], wA + (size_t)(m0+row)*CIN + k0 + colg*8);
    }
    #pragma unroll
    for (int p = 0; p < 4; ++p) {
      int g = gh + 2*p;
      __attribute__((aligned(16))) __bf16 tmp[8];
      #pragma unroll
      for (int j = 0; j < 8; ++j)
        tmp[j] = (__bf16)Hb[(size_t)(k0 + g*8 + j)*CN + nn];
      *(uint4*)&Bt[nn*72 + g*8] = *(uint4*)tmp;
    }
    __syncthreads();
    #pragma unroll
    for (int kk = 0; kk < 2; ++kk) {
      short8 a[4], bb[2];
      #pragma unroll
      for (int mi = 0; mi < 4; ++mi)
        a[mi] = *(short8*)&At[(mi*16 + l15)*72 + kk*32 + q*8];
      #pragma unroll
      for (int ni = 0; ni < 2; ++ni)
        bb[ni] = *(short8*)&Bt[(w*32 + ni*16 + l15)*72 + kk*32 + q*8];
      #pragma unroll
      for (int mi = 0; mi < 4; ++mi)
        #pragma unroll
        for (int ni = 0; ni < 2; ++ni)
          acc[mi][ni] = MFMA(a[mi], bb[ni], acc[mi][ni]);
    }
    __syncthreads();
  }

  #pragma unroll
  for (int mi = 0; mi < 4; ++mi)
    #pragma unroll
    for (int ni = 0; ni < 2; ++ni)
      #pragma unroll
      for (int r = 0; r < 4; ++r) {
        int m = m0 + mi*16 + q*4 + r;
        int n = w*32 + ni*16 + l15;
        G[((size_t)b*CM + m)*CN + n] = (__bf16)(acc[mi][ni][r] + bA[m]);
      }
}

// ---------------------------------------------------------------------------
extern "C" void kernel_launch(void* const* d_in, const int* in_sizes, int n_in,
                              void* d_out, int out_size, void* d_ws, size_t ws_size,
                              hipStream_t stream)
{
  (void)in_sizes; (void)n_in; (void)out_size;
  const float* x  = (const float*)d_in[0];
  const float* wA = (const float*)d_in[1];
  const float* bA = (const float*)d_in[2];
  const float* wB = (const float*)d_in[3];
  const float* bB = (const float*)d_in[4];
  const float* wV = (const float*)d_in[5];
  const float* bV = (const float*)d_in[6];
  float* out = (float*)d_out;

  char* ws = (char*)d_ws;
  const size_t szXT    = (size_t)BATCH*HW*CIN*2;    // 51,380,224
  const size_t szXBF   = (size_t)BATCH*CIN*HW*2;    // 51,380,224
  const size_t szWBF   = (size_t)(128*512 + 128*512 + 512*512)*2; // 786,432
  const size_t szBVB   = (size_t)BATCH*CN*HW*2;     // 12,845,056
  const size_t szAttVT = (size_t)BATCH*HW*CN*2;     // 12,845,056
  const size_t szH     = (size_t)BATCH*CIN*CN*4;    //  4,194,304
  const size_t szG     = (size_t)BATCH*CM*CN*2;     //  2,097,152
  const size_t szStats = (size_t)BATCH*CN*4*2;      //     16,384
  const size_t needMain = szXT + szXBF + szWBF + szBVB + szAttVT + szH + szG + szStats;

  if (ws_size >= needMain) {
    char* p = ws;
    __bf16* xT    = (__bf16*)p; p += szXT;
    __bf16* xbf   = (__bf16*)p; p += szXBF;
    __bf16* Wbf   = (__bf16*)p; p += szWBF;
    __bf16* BVB   = (__bf16*)p; p += szBVB;
    __bf16* attVT = (__bf16*)p; p += szAttVT;
    float*  H     = (float*)p;  p += szH;
    __bf16* G     = (__bf16*)p; p += szG;
    float*  sm    = (float*)p;  p += (size_t)BATCH*CN*4;
    float*  sinv  = (float*)p;
    __bf16* wAbf  = Wbf + 2*128*512;

    wcast_kernel      <<<dim3(192),     256, 0, stream>>>(wB, wV, wA, Wbf);
    transpose_x_kernel<<<dim3(49,4,16), 256, 0, stream>>>(x, xT, xbf);
    conv_bv_kernel    <<<dim3(49,16),   256, 0, stream>>>(Wbf, xT, bB, bV, BVB, attVT);
    bstats_kernel     <<<dim3(512),     256, 0, stream>>>(BVB, sm, sinv);
    hipMemsetAsync(H, 0, szH, stream);
    h_gemm_kernel     <<<dim3(4,16,7),  256, 0, stream>>>(xbf, BVB, sm, sinv, H);
    g_gemm_kernel     <<<dim3(8,16),    256, 0, stream>>>(wAbf, bA, H, G);
    z_gemm_kernel     <<<dim3(4,49,16), 256, 0, stream>>>(G, attVT, out);
  } else {
    // fallback: R2 layout (44.8 MB)
    const size_t szBV = (size_t)BATCH*CBV*HW*2;
    __bf16* BV    = (__bf16*)(ws);
    __bf16* attVT = (__bf16*)(ws + szBV);
    float*  H     = (float*) (ws + szBV + szAttVT);
    __bf16* G     = (__bf16*)(ws + szBV + szAttVT + szH);

    conv_bv_gather_kernel<<<dim3(49,16),   256, 0, stream>>>(x, wB, bB, wV, bV, BV);
    softmax_b_kernel     <<<dim3(128,16),  256, 0, stream>>>(BV);
    softmax_v_t_kernel   <<<dim3(49,16),   256, 0, stream>>>(BV, attVT);
    hipMemsetAsync(H, 0, szH, stream);
    h_gemm_f32_kernel    <<<dim3(8,16,7),  256, 0, stream>>>(x, BV, H);
    g_gemm_f32w_kernel   <<<dim3(8,16),    256, 0, stream>>>(wA, bA, H, G);
    z_gemm_kernel        <<<dim3(4,49,16), 256, 0, stream>>>(G, attVT, out);
  }
}

// Round 5
// 305.005 us; speedup vs baseline: 1.0212x; 1.0212x over previous
//
#include <hip/hip_runtime.h>
#include <hip/hip_bf16.h>

#define BATCH 16
#define CIN   512
#define HW    3136
#define CM    512
#define CN    128
#define CBV   256

typedef short short8 __attribute__((ext_vector_type(8)));
typedef float f32x4  __attribute__((ext_vector_type(4)));

#define MFMA(a,b,c) __builtin_amdgcn_mfma_f32_16x16x32_bf16((a),(b),(c),0,0,0)

// convert 8 consecutive fp32 -> 8 bf16, store as one 16B chunk (LDS or global)
__device__ __forceinline__ void cvt_store8(__bf16* dst, const float* src) {
  const f32x4 a = *(const f32x4*)src;
  const f32x4 b = *(const f32x4*)(src + 4);
  __attribute__((aligned(16))) __bf16 t[8];
  t[0] = (__bf16)a[0]; t[1] = (__bf16)a[1]; t[2] = (__bf16)a[2]; t[3] = (__bf16)a[3];
  t[4] = (__bf16)b[0]; t[5] = (__bf16)b[1]; t[6] = (__bf16)b[2]; t[7] = (__bf16)b[3];
  *(uint4*)dst = *(uint4*)t;
}

// ---------------------------------------------------------------------------
// Kernel 0a: cast weights fp32->bf16 into Wbf = [wB 128x512 | wV 128x512 | wA 512x512]
// ---------------------------------------------------------------------------
__global__ __launch_bounds__(256) void wcast_kernel(
    const float* __restrict__ wB, const float* __restrict__ wV,
    const float* __restrict__ wA, __bf16* __restrict__ Wbf)
{
  size_t i = (size_t)blockIdx.x*2048 + (size_t)threadIdx.x*8;
  const float* src; size_t off;
  if (i < 65536)       { src = wB; off = i; }
  else if (i < 131072) { src = wV; off = i - 65536; }
  else                 { src = wA; off = i - 131072; }
  cvt_store8(Wbf + i, src + off);
}

// ---------------------------------------------------------------------------
// Kernel 0b: transpose+cast x[b][c][s] fp32 -> xT[b][s][c] bf16.
// tile 128c x 64s. XOR-octet-swizzled LDS: storage octet = (c>>3) ^ ((s>>3)&7).
// Writes are c-pair dwords (b32, 2-way bank max = free); reads are b128.
// ---------------------------------------------------------------------------
__global__ __launch_bounds__(256) void transpose_x_kernel(
    const float* __restrict__ x, __bf16* __restrict__ xT)
{
  const int s0 = blockIdx.x * 64;
  const int c0 = blockIdx.y * 128;
  const int b  = blockIdx.z;
  const int tid = threadIdx.x;
  __shared__ __attribute__((aligned(16))) __bf16 T[64*136];

  const float* xb = x + ((size_t)b*CIN + c0)*HW + s0;
  const int colg = tid & 7;   // s-octet (s = colg*8 + j)
  const int pr   = tid >> 3;  // c-pair index 0..31

  #pragma unroll
  for (int p = 0; p < 2; ++p) {
    int c = (pr + 32*p) * 2;                 // even c; pair = (c, c+1)
    const float* r0 = xb + (size_t)c*HW + colg*8;
    const float* r1 = r0 + HW;
    f32x4 a0 = *(const f32x4*)r0, a1 = *(const f32x4*)(r0 + 4);
    f32x4 b0 = *(const f32x4*)r1, b1 = *(const f32x4*)(r1 + 4);
    float va[8] = {a0[0],a0[1],a0[2],a0[3],a1[0],a1[1],a1[2],a1[3]};
    float vb[8] = {b0[0],b0[1],b0[2],b0[3],b1[0],b1[1],b1[2],b1[3]};
    const int off = ((c >> 3) ^ colg) * 8 + (c & 7);   // even -> dword aligned
    #pragma unroll
    for (int j = 0; j < 8; ++j) {
      int s = colg*8 + j;
      __attribute__((aligned(4))) __bf16 pairv[2] = { (__bf16)va[j], (__bf16)vb[j] };
      *(unsigned int*)&T[s*136 + off] = *(unsigned int*)pairv;
    }
  }
  __syncthreads();

  __bf16* dst = xT + ((size_t)b*HW + s0)*CIN + c0;
  const int cg = tid & 15, sr = tid >> 4;
  #pragma unroll
  for (int p = 0; p < 4; ++p) {
    int row = sr + 16*p;
    int oct = cg ^ ((row >> 3) & 7);         // toggles low 3 bits only
    *(uint4*)&dst[(size_t)row*CIN + cg*8] = *(uint4*)&T[row*136 + oct*8];
  }
}

// ---------------------------------------------------------------------------
// Kernel 1: conv (wB|wV) @ x + bias with FUSED V-softmax.
//   writes BVB[b][n][s] (raw B-half, n<128, bf16)
//   writes attVT[b][s][n] (softmaxed V-half, transposed, bf16)
// ---------------------------------------------------------------------------
__global__ __launch_bounds__(256) void conv_bv_kernel(
    const __bf16* __restrict__ Wbf, const __bf16* __restrict__ xT,
    const float* __restrict__ bB, const float* __restrict__ bV,
    __bf16* __restrict__ BVB, __bf16* __restrict__ attVT)
{
  const int s0  = blockIdx.x * 64;
  const int b   = blockIdx.y;
  const int tid = threadIdx.x;
  const int lane = tid & 63, w = tid >> 6;
  const int l15  = lane & 15, q = lane >> 4;

  __shared__ __attribute__((aligned(16))) char smem[46080]; // Wt 36864 | Xt 9216; aliased by T
  __bf16* Wt = (__bf16*)smem;            // [256][72]
  __bf16* Xt = (__bf16*)(smem + 36864);  // [64][72]
  __bf16* T  = (__bf16*)smem;            // [64][136] (epilogue alias)
  __shared__ float Vm[2][64];
  __shared__ float Vs[2][64];

  f32x4 acc[4][4] = {};
  const __bf16* xTb = xT + (size_t)b*HW*CIN;
  const int colg = tid & 7, row0 = tid >> 3;

  for (int k0 = 0; k0 < CIN; k0 += 64) {
    #pragma unroll
    for (int p = 0; p < 8; ++p) {
      int row = row0 + 32*p;
      *(uint4*)&Wt[row*72 + colg*8] = *(const uint4*)(Wbf + (size_t)row*CIN + k0 + colg*8);
    }
    #pragma unroll
    for (int p = 0; p < 2; ++p) {
      int row = row0 + 32*p;
      *(uint4*)&Xt[row*72 + colg*8] = *(const uint4*)(xTb + (size_t)(s0+row)*CIN + k0 + colg*8);
    }
    __syncthreads();
    #pragma unroll
    for (int kk = 0; kk < 2; ++kk) {
      short8 a[4], bb[4];
      #pragma unroll
      for (int mi = 0; mi < 4; ++mi)
        a[mi] = *(short8*)&Wt[(w*64 + mi*16 + l15)*72 + kk*32 + q*8];
      #pragma unroll
      for (int si = 0; si < 4; ++si)
        bb[si] = *(short8*)&Xt[(si*16 + l15)*72 + kk*32 + q*8];
      #pragma unroll
      for (int mi = 0; mi < 4; ++mi)
        #pragma unroll
        for (int si = 0; si < 4; ++si)
          acc[mi][si] = MFMA(a[mi], bb[si], acc[mi][si]);
    }
    __syncthreads();
  }

  float bias[4][4];
  #pragma unroll
  for (int mi = 0; mi < 4; ++mi)
    #pragma unroll
    for (int r = 0; r < 4; ++r) {
      int nch = w*64 + mi*16 + q*4 + r;
      bias[mi][r] = (nch < CN) ? bB[nch] : bV[nch - CN];
    }

  if (w < 2) {
    const size_t outb = (size_t)b * CN * HW;
    #pragma unroll
    for (int mi = 0; mi < 4; ++mi)
      #pragma unroll
      for (int si = 0; si < 4; ++si) {
        int s = s0 + si*16 + l15;
        #pragma unroll
        for (int r = 0; r < 4; ++r) {
          int nch = w*64 + mi*16 + q*4 + r;
          BVB[outb + (size_t)nch*HW + s] = (__bf16)(acc[mi][si][r] + bias[mi][r]);
        }
      }
  } else {
    #pragma unroll
    for (int si = 0; si < 4; ++si) {
      float m = -1e30f;
      #pragma unroll
      for (int mi = 0; mi < 4; ++mi)
        #pragma unroll
        for (int r = 0; r < 4; ++r)
          m = fmaxf(m, acc[mi][si][r] + bias[mi][r]);
      m = fmaxf(m, __shfl_xor(m, 16));
      m = fmaxf(m, __shfl_xor(m, 32));
      if (q == 0) Vm[w-2][si*16 + l15] = m;
    }
  }
  __syncthreads();
  if (w >= 2) {
    #pragma unroll
    for (int si = 0; si < 4; ++si) {
      int idx = si*16 + l15;
      float ms = fmaxf(Vm[0][idx], Vm[1][idx]);
      float ssum = 0.f;
      #pragma unroll
      for (int mi = 0; mi < 4; ++mi)
        #pragma unroll
        for (int r = 0; r < 4; ++r) {
          float e = __expf(acc[mi][si][r] + bias[mi][r] - ms);
          acc[mi][si][r] = e;
          ssum += e;
        }
      ssum += __shfl_xor(ssum, 16);
      ssum += __shfl_xor(ssum, 32);
      if (q == 0) Vs[w-2][idx] = ssum;
    }
  }
  __syncthreads();
  if (w >= 2) {
    #pragma unroll
    for (int si = 0; si < 4; ++si) {
      int idx = si*16 + l15;
      float inv = 1.0f / (Vs[0][idx] + Vs[1][idx]);
      #pragma unroll
      for (int mi = 0; mi < 4; ++mi)
        #pragma unroll
        for (int r = 0; r < 4; ++r) {
          int j = (w-2)*64 + mi*16 + q*4 + r;
          T[idx*136 + j] = (__bf16)(acc[mi][si][r] * inv);
        }
    }
  }
  __syncthreads();
  __bf16* dst = attVT + ((size_t)b*HW + s0)*CN;
  #pragma unroll
  for (int k = 0; k < 4; ++k) {
    int chunk = tid + 256*k;
    int row = chunk >> 4, oct = chunk & 15;
    *(uint4*)&dst[(size_t)row*CN + oct*8] = *(uint4*)&T[row*136 + oct*8];
  }
}

// ---------------------------------------------------------------------------
// Kernel 2: per-(b,n) row stats of BVB: max and 1/sum(exp(v-max)).  2048 rows.
// ---------------------------------------------------------------------------
__global__ __launch_bounds__(256) void bstats_kernel(
    const __bf16* __restrict__ BVB, float* __restrict__ sm, float* __restrict__ sinv)
{
  const int row = blockIdx.x*4 + (threadIdx.x >> 6);
  const int lane = threadIdx.x & 63;
  const __bf16* rp = BVB + (size_t)row*HW;

  uint4 raw[7];
  float mx = -1e30f;
  #pragma unroll
  for (int i = 0; i < 6; ++i) {
    raw[i] = *(const uint4*)(rp + (lane + 64*i)*8);
    const __bf16* v = (const __bf16*)&raw[i];
    #pragma unroll
    for (int j = 0; j < 8; ++j) mx = fmaxf(mx, (float)v[j]);
  }
  if (lane < 8) {
    raw[6] = *(const uint4*)(rp + (lane + 384)*8);
    const __bf16* v = (const __bf16*)&raw[6];
    #pragma unroll
    for (int j = 0; j < 8; ++j) mx = fmaxf(mx, (float)v[j]);
  }
  #pragma unroll
  for (int off = 1; off < 64; off <<= 1) mx = fmaxf(mx, __shfl_xor(mx, off));

  float sum = 0.f;
  #pragma unroll
  for (int i = 0; i < 6; ++i) {
    const __bf16* v = (const __bf16*)&raw[i];
    #pragma unroll
    for (int j = 0; j < 8; ++j) sum += __expf((float)v[j] - mx);
  }
  if (lane < 8) {
    const __bf16* v = (const __bf16*)&raw[6];
    #pragma unroll
    for (int j = 0; j < 8; ++j) sum += __expf((float)v[j] - mx);
  }
  #pragma unroll
  for (int off = 1; off < 64; off <<= 1) sum += __shfl_xor(sum, off);

  if (lane == 0) { sm[row] = mx; sinv[row] = 1.0f / sum; }
}

// ---------------------------------------------------------------------------
// Kernel 3: H[b][c][n] += sum_s x[b][c][s] * softmaxB(BVB)[n][s]
// tile 128c x 128n, split-K=7, fp32 x converted at staging, fp32 atomics
// ---------------------------------------------------------------------------
__global__ __launch_bounds__(256) void h_gemm_kernel(
    const float* __restrict__ x, const __bf16* __restrict__ BVB,
    const float* __restrict__ sm, const float* __restrict__ sinv,
    float* __restrict__ H)
{
  const int c0 = blockIdx.x * 128, b = blockIdx.y, kc = blockIdx.z;
  const int tid = threadIdx.x, lane = tid & 63, w = tid >> 6;
  const int l15 = lane & 15, q = lane >> 4;

  __shared__ __attribute__((aligned(16))) __bf16 At[128*72];  // x tile [c][s]
  __shared__ __attribute__((aligned(16))) __bf16 Bt[128*72];  // attB tile [n][s]
  f32x4 acc[8][2] = {};

  const float* xb = x + ((size_t)b*CIN + c0)*HW;
  const __bf16* ab = BVB + (size_t)b*CN*HW;
  const float* smb = sm + b*CN;
  const float* sib = sinv + b*CN;
  const int colg = tid & 7, row0 = tid >> 3;

  for (int ki = 0; ki < 7; ++ki) {
    int k0 = kc*448 + ki*64;
    #pragma unroll
    for (int p = 0; p < 4; ++p) {
      int row = row0 + 32*p;
      cvt_store8(&At[row*72 + colg*8], xb + (size_t)row*HW + k0 + colg*8);
    }
    #pragma unroll
    for (int p = 0; p < 4; ++p) {
      int row = row0 + 32*p;
      uint4 rawv = *(const uint4*)(ab + (size_t)row*HW + k0 + colg*8);
      const __bf16* v = (const __bf16*)&rawv;
      float mrow = smb[row], irow = sib[row];
      __attribute__((aligned(16))) __bf16 t[8];
      #pragma unroll
      for (int j = 0; j < 8; ++j)
        t[j] = (__bf16)(__expf((float)v[j] - mrow) * irow);
      *(uint4*)&Bt[row*72 + colg*8] = *(uint4*)t;
    }
    __syncthreads();
    #pragma unroll
    for (int kk = 0; kk < 2; ++kk) {
      short8 a[8], bb[2];
      #pragma unroll
      for (int mi = 0; mi < 8; ++mi)
        a[mi] = *(short8*)&At[(mi*16 + l15)*72 + kk*32 + q*8];
      #pragma unroll
      for (int ni = 0; ni < 2; ++ni)
        bb[ni] = *(short8*)&Bt[(w*32 + ni*16 + l15)*72 + kk*32 + q*8];
      #pragma unroll
      for (int mi = 0; mi < 8; ++mi)
        #pragma unroll
        for (int ni = 0; ni < 2; ++ni)
          acc[mi][ni] = MFMA(a[mi], bb[ni], acc[mi][ni]);
    }
    __syncthreads();
  }

  float* Hb = H + (size_t)b*CIN*CN;
  #pragma unroll
  for (int mi = 0; mi < 8; ++mi)
    #pragma unroll
    for (int ni = 0; ni < 2; ++ni)
      #pragma unroll
      for (int r = 0; r < 4; ++r) {
        int c = c0 + mi*16 + q*4 + r;
        int n = w*32 + ni*16 + l15;
        atomicAdd(&Hb[c*CN + n], acc[mi][ni][r]);
      }
}

// ---------------------------------------------------------------------------
// Kernel 4: G[b] = wA @ H[b] + bA  (M=512 in 64-tiles, N=128, K=512) -> bf16
// ---------------------------------------------------------------------------
__global__ __launch_bounds__(256) void g_gemm_kernel(
    const __bf16* __restrict__ wAbf, const float* __restrict__ bA,
    const float* __restrict__ H, __bf16* __restrict__ G)
{
  const int m0 = blockIdx.x * 64, b = blockIdx.y;
  const int tid = threadIdx.x, lane = tid & 63, w = tid >> 6;
  const int l15 = lane & 15, q = lane >> 4;

  __shared__ __attribute__((aligned(16))) __bf16 At[64*72];
  __shared__ __attribute__((aligned(16))) __bf16 Bt[128*72];
  f32x4 acc[4][2] = {};

  const float* Hb = H + (size_t)b*CIN*CN;
  const int colg = tid & 7, row0 = tid >> 3;
  const int nn = tid & 127, gh = tid >> 7;

  for (int k0 = 0; k0 < CIN; k0 += 64) {
    #pragma unroll
    for (int p = 0; p < 2; ++p) {
      int row = row0 + 32*p;
      *(uint4*)&At[row*72 + colg*8] = *(const uint4*)(wAbf + (size_t)(m0+row)*CIN + k0 + colg*8);
    }
    #pragma unroll
    for (int p = 0; p < 4; ++p) {
      int g = gh + 2*p;
      __attribute__((aligned(16))) __bf16 tmp[8];
      #pragma unroll
      for (int j = 0; j < 8; ++j)
        tmp[j] = (__bf16)Hb[(size_t)(k0 + g*8 + j)*CN + nn];
      *(uint4*)&Bt[nn*72 + g*8] = *(uint4*)tmp;
    }
    __syncthreads();
    #pragma unroll
    for (int kk = 0; kk < 2; ++kk) {
      short8 a[4], bb[2];
      #pragma unroll
      for (int mi = 0; mi < 4; ++mi)
        a[mi] = *(short8*)&At[(mi*16 + l15)*72 + kk*32 + q*8];
      #pragma unroll
      for (int ni = 0; ni < 2; ++ni)
        bb[ni] = *(short8*)&Bt[(w*32 + ni*16 + l15)*72 + kk*32 + q*8];
      #pragma unroll
      for (int mi = 0; mi < 4; ++mi)
        #pragma unroll
        for (int ni = 0; ni < 2; ++ni)
          acc[mi][ni] = MFMA(a[mi], bb[ni], acc[mi][ni]);
    }
    __syncthreads();
  }

  #pragma unroll
  for (int mi = 0; mi < 4; ++mi)
    #pragma unroll
    for (int ni = 0; ni < 2; ++ni)
      #pragma unroll
      for (int r = 0; r < 4; ++r) {
        int m = m0 + mi*16 + q*4 + r;
        int n = w*32 + ni*16 + l15;
        G[((size_t)b*CM + m)*CN + n] = (__bf16)(acc[mi][ni][r] + bA[m]);
      }
}

// ---------------------------------------------------------------------------
// Kernel 5: Z[b][m][s] = sum_n G[b][m][n] * attVT[b][s][n]  -> fp32 output
// ---------------------------------------------------------------------------
__global__ __launch_bounds__(256) void z_gemm_kernel(
    const __bf16* __restrict__ G, const __bf16* __restrict__ attVT,
    float* __restrict__ out)
{
  const int m0 = blockIdx.x * 128, s0 = blockIdx.y * 64, b = blockIdx.z;
  const int tid = threadIdx.x, lane = tid & 63, w = tid >> 6;
  const int l15 = lane & 15, q = lane >> 4;

  __shared__ __attribute__((aligned(16))) __bf16 At[128*136];
  __shared__ __attribute__((aligned(16))) __bf16 Bt[64*136];

  const __bf16* Gb = G + ((size_t)b*CM + m0)*CN;
  const __bf16* Vb = attVT + ((size_t)b*HW + s0)*CN;
  const int g = tid & 15, r0 = tid >> 4;
  #pragma unroll
  for (int p = 0; p < 8; ++p) {
    int row = r0 + 16*p;
    *(uint4*)&At[row*136 + g*8] = *(const uint4*)(Gb + (size_t)row*CN + g*8);
  }
  #pragma unroll
  for (int p = 0; p < 4; ++p) {
    int row = r0 + 16*p;
    *(uint4*)&Bt[row*136 + g*8] = *(const uint4*)(Vb + (size_t)row*CN + g*8);
  }
  __syncthreads();

  f32x4 acc[8] = {};
  #pragma unroll
  for (int kk = 0; kk < 4; ++kk) {
    short8 bb = *(short8*)&Bt[(w*16 + l15)*136 + kk*32 + q*8];
    #pragma unroll
    for (int mi = 0; mi < 8; ++mi) {
      short8 a = *(short8*)&At[(mi*16 + l15)*136 + kk*32 + q*8];
      acc[mi] = MFMA(a, bb, acc[mi]);
    }
  }

  const int s = s0 + w*16 + l15;
  #pragma unroll
  for (int mi = 0; mi < 8; ++mi)
    #pragma unroll
    for (int r = 0; r < 4; ++r) {
      int m = m0 + mi*16 + q*4 + r;
      out[((size_t)b*CM + m)*HW + s] = acc[mi][r];
    }
}

// ---------------------------------------------------------------------------
extern "C" void kernel_launch(void* const* d_in, const int* in_sizes, int n_in,
                              void* d_out, int out_size, void* d_ws, size_t ws_size,
                              hipStream_t stream)
{
  (void)in_sizes; (void)n_in; (void)out_size; (void)ws_size;
  const float* x  = (const float*)d_in[0];
  const float* wA = (const float*)d_in[1];
  const float* bA = (const float*)d_in[2];
  const float* wB = (const float*)d_in[3];
  const float* bB = (const float*)d_in[4];
  const float* wV = (const float*)d_in[5];
  const float* bV = (const float*)d_in[6];
  float* out = (float*)d_out;

  char* ws = (char*)d_ws;
  const size_t szXT    = (size_t)BATCH*HW*CIN*2;    // 51,380,224
  const size_t szWBF   = (size_t)(128*512 + 128*512 + 512*512)*2; // 786,432
  const size_t szBVB   = (size_t)BATCH*CN*HW*2;     // 12,845,056
  const size_t szAttVT = (size_t)BATCH*HW*CN*2;     // 12,845,056
  const size_t szH     = (size_t)BATCH*CIN*CN*4;    //  4,194,304

  char* p = ws;
  __bf16* xT    = (__bf16*)p; p += szXT;
  __bf16* Wbf   = (__bf16*)p; p += szWBF;
  __bf16* BVB   = (__bf16*)p; p += szBVB;
  __bf16* attVT = (__bf16*)p; p += szAttVT;
  float*  H     = (float*)p;  p += szH;
  __bf16* G     = (__bf16*)p; p += (size_t)BATCH*CM*CN*2;
  float*  sm    = (float*)p;  p += (size_t)BATCH*CN*4;
  float*  sinv  = (float*)p;
  __bf16* wAbf  = Wbf + 2*128*512;

  wcast_kernel      <<<dim3(192),     256, 0, stream>>>(wB, wV, wA, Wbf);
  transpose_x_kernel<<<dim3(49,4,16), 256, 0, stream>>>(x, xT);
  conv_bv_kernel    <<<dim3(49,16),   256, 0, stream>>>(Wbf, xT, bB, bV, BVB, attVT);
  bstats_kernel     <<<dim3(512),     256, 0, stream>>>(BVB, sm, sinv);
  hipMemsetAsync(H, 0, szH, stream);
  h_gemm_kernel     <<<dim3(4,16,7),  256, 0, stream>>>(x, BVB, sm, sinv, H);
  g_gemm_kernel     <<<dim3(8,16),    256, 0, stream>>>(wAbf, bA, H, G);
  z_gemm_kernel     <<<dim3(4,49,16), 256, 0, stream>>>(G, attVT, out);
}

// Round 6
// 299.445 us; speedup vs baseline: 1.0401x; 1.0186x over previous
//
#include <hip/hip_runtime.h>
#include <hip/hip_bf16.h>

#define BATCH 16
#define CIN   512
#define HW    3136
#define CM    512
#define CN    128

typedef short short8 __attribute__((ext_vector_type(8)));
typedef float f32x4  __attribute__((ext_vector_type(4)));

#define MFMA(a,b,c) __builtin_amdgcn_mfma_f32_16x16x32_bf16((a),(b),(c),0,0,0)

// convert 8 consecutive fp32 -> 8 bf16, store as one 16B chunk (LDS or global)
__device__ __forceinline__ void cvt_store8(__bf16* dst, const float* src) {
  const f32x4 a = *(const f32x4*)src;
  const f32x4 b = *(const f32x4*)(src + 4);
  __attribute__((aligned(16))) __bf16 t[8];
  t[0] = (__bf16)a[0]; t[1] = (__bf16)a[1]; t[2] = (__bf16)a[2]; t[3] = (__bf16)a[3];
  t[4] = (__bf16)b[0]; t[5] = (__bf16)b[1]; t[6] = (__bf16)b[2]; t[7] = (__bf16)b[3];
  *(uint4*)dst = *(uint4*)t;
}

// ---------------------------------------------------------------------------
// Kernel 1: conv (wB|wV) @ x + bias, x transposed IN-LDS (XOR-octet swizzle),
// fused V-softmax (transposed attVT out) and fused B-softmax row sums (atomics).
//   BVB[b][n][s]   raw B-half conv out (bf16)
//   attVT[b][s][n] softmaxed V-half, transposed (bf16)
//   bsum[b][n]     += sum_s exp(BVB[b][n][s])   (fp32, atomic)
// block: 64 s-cols x 256 channels; waves 0,1 = B half; waves 2,3 = V half.
// ---------------------------------------------------------------------------
__global__ __launch_bounds__(256) void conv_bv_kernel(
    const float* __restrict__ x,
    const float* __restrict__ wB, const float* __restrict__ wV,
    const float* __restrict__ bB, const float* __restrict__ bV,
    __bf16* __restrict__ BVB, __bf16* __restrict__ attVT,
    float* __restrict__ bsum)
{
  const int s0  = blockIdx.x * 64;
  const int b   = blockIdx.y;
  const int tid = threadIdx.x;
  const int lane = tid & 63, w = tid >> 6;
  const int l15  = lane & 15, q = lane >> 4;

  __shared__ __attribute__((aligned(16))) char smem[46080]; // Wt 36864 | Xt 9216
  __bf16* Wt = (__bf16*)smem;            // [256][72]  (n-major, k-contig)
  __bf16* Xt = (__bf16*)(smem + 36864);  // [64][72]   (s-major, XOR-swizzled octets)
  __bf16* T  = (__bf16*)smem;            // [64][136]  epilogue alias
  __shared__ float Vm[2][64];
  __shared__ float Vs[2][64];

  f32x4 acc[4][4] = {};
  const float* xb = x + (size_t)b*CIN*HW + s0;
  const int colg = tid & 7, row0 = tid >> 3;  // W staging + X s-octet/c-pair map
  const int cl = 2*(tid >> 3);                // even c_local (pair cl, cl+1)

  for (int k0 = 0; k0 < CIN; k0 += 64) {
    // stage W (256n x 64k) with fp32->bf16 convert (L2-resident)
    #pragma unroll
    for (int p = 0; p < 8; ++p) {
      int row = row0 + 32*p;
      const float* src = (row < 128) ? (wB + row*512) : (wV + (row-128)*512);
      cvt_store8(&Wt[row*72 + colg*8], src + k0 + colg*8);
    }
    // stage x-tile transposed: coalesced fp32 loads of rows (cl, cl+1),
    // pair-dword writes into Xt[s][c] at swizzled octet (c>>3)^(s>>3).
    {
      const float* r0 = xb + (size_t)(k0 + cl)*HW + colg*8;
      const float* r1 = r0 + HW;
      f32x4 a0 = *(const f32x4*)r0, a1 = *(const f32x4*)(r0 + 4);
      f32x4 b0 = *(const f32x4*)r1, b1 = *(const f32x4*)(r1 + 4);
      float va[8] = {a0[0],a0[1],a0[2],a0[3],a1[0],a1[1],a1[2],a1[3]};
      float vb[8] = {b0[0],b0[1],b0[2],b0[3],b1[0],b1[1],b1[2],b1[3]};
      const int off = ((cl >> 3) ^ colg)*8 + (cl & 7);  // even -> dword aligned
      #pragma unroll
      for (int j = 0; j < 8; ++j) {
        int s = colg*8 + j;
        __attribute__((aligned(4))) __bf16 pairv[2] = { (__bf16)va[j], (__bf16)vb[j] };
        *(unsigned int*)&Xt[s*72 + off] = *(unsigned int*)pairv;
      }
    }
    __syncthreads();
    #pragma unroll
    for (int kk = 0; kk < 2; ++kk) {
      short8 a[4], bb[4];
      #pragma unroll
      for (int mi = 0; mi < 4; ++mi)
        a[mi] = *(short8*)&Wt[(w*64 + mi*16 + l15)*72 + kk*32 + q*8];
      #pragma unroll
      for (int si = 0; si < 4; ++si) {
        int s = si*16 + l15;
        int oct = (kk*4 + q) ^ (si*2 + (l15 >> 3));
        bb[si] = *(short8*)&Xt[s*72 + oct*8];
      }
      #pragma unroll
      for (int mi = 0; mi < 4; ++mi)
        #pragma unroll
        for (int si = 0; si < 4; ++si)
          acc[mi][si] = MFMA(a[mi], bb[si], acc[mi][si]);
    }
    __syncthreads();
  }

  float bias[4][4];
  #pragma unroll
  for (int mi = 0; mi < 4; ++mi)
    #pragma unroll
    for (int r = 0; r < 4; ++r) {
      int nch = w*64 + mi*16 + q*4 + r;
      bias[mi][r] = (nch < CN) ? bB[nch] : bV[nch - CN];
    }

  if (w < 2) {
    // B half: write raw bf16 rows + accumulate per-n sum of exp (no max needed:
    // |v| <~ 5, exp safe in fp32; matches h_gemm's exp of the bf16-rounded value)
    const size_t outb = (size_t)b * CN * HW;
    float psum[4][4] = {};
    #pragma unroll
    for (int mi = 0; mi < 4; ++mi)
      #pragma unroll
      for (int si = 0; si < 4; ++si) {
        int s = s0 + si*16 + l15;
        #pragma unroll
        for (int r = 0; r < 4; ++r) {
          int nch = w*64 + mi*16 + q*4 + r;
          __bf16 bv = (__bf16)(acc[mi][si][r] + bias[mi][r]);
          BVB[outb + (size_t)nch*HW + s] = bv;
          psum[mi][r] += __expf((float)bv);
        }
      }
    #pragma unroll
    for (int mi = 0; mi < 4; ++mi)
      #pragma unroll
      for (int r = 0; r < 4; ++r) {
        float v = psum[mi][r];
        v += __shfl_xor(v, 1); v += __shfl_xor(v, 2);
        v += __shfl_xor(v, 4); v += __shfl_xor(v, 8);
        if (l15 == 0) {
          int nch = w*64 + mi*16 + q*4 + r;
          atomicAdd(&bsum[b*CN + nch], v);
        }
      }
  } else {
    // V half: per-s max over its 128 V channels
    #pragma unroll
    for (int si = 0; si < 4; ++si) {
      float m = -1e30f;
      #pragma unroll
      for (int mi = 0; mi < 4; ++mi)
        #pragma unroll
        for (int r = 0; r < 4; ++r)
          m = fmaxf(m, acc[mi][si][r] + bias[mi][r]);
      m = fmaxf(m, __shfl_xor(m, 16));
      m = fmaxf(m, __shfl_xor(m, 32));
      if (q == 0) Vm[w-2][si*16 + l15] = m;
    }
  }
  __syncthreads();
  if (w >= 2) {
    #pragma unroll
    for (int si = 0; si < 4; ++si) {
      int idx = si*16 + l15;
      float ms = fmaxf(Vm[0][idx], Vm[1][idx]);
      float ssum = 0.f;
      #pragma unroll
      for (int mi = 0; mi < 4; ++mi)
        #pragma unroll
        for (int r = 0; r < 4; ++r) {
          float e = __expf(acc[mi][si][r] + bias[mi][r] - ms);
          acc[mi][si][r] = e;
          ssum += e;
        }
      ssum += __shfl_xor(ssum, 16);
      ssum += __shfl_xor(ssum, 32);
      if (q == 0) Vs[w-2][idx] = ssum;
    }
  }
  __syncthreads();
  if (w >= 2) {
    #pragma unroll
    for (int si = 0; si < 4; ++si) {
      int idx = si*16 + l15;
      float inv = 1.0f / (Vs[0][idx] + Vs[1][idx]);
      #pragma unroll
      for (int mi = 0; mi < 4; ++mi)
        #pragma unroll
        for (int r = 0; r < 4; ++r) {
          int j = (w-2)*64 + mi*16 + q*4 + r;
          T[idx*136 + j] = (__bf16)(acc[mi][si][r] * inv);
        }
    }
  }
  __syncthreads();
  __bf16* dst = attVT + ((size_t)b*HW + s0)*CN;
  #pragma unroll
  for (int k = 0; k < 4; ++k) {
    int chunk = tid + 256*k;
    int row = chunk >> 4, oct = chunk & 15;
    *(uint4*)&dst[(size_t)row*CN + oct*8] = *(uint4*)&T[row*136 + oct*8];
  }
}

// ---------------------------------------------------------------------------
// Kernel 2: H[b][c][n] += sum_s x[b][c][s] * (exp(BVB[n][s]) / bsum[n])
// tile 128c x 128n, split-K=7, fp32 x converted + softmax applied at staging
// ---------------------------------------------------------------------------
__global__ __launch_bounds__(256) void h_gemm_kernel(
    const float* __restrict__ x, const __bf16* __restrict__ BVB,
    const float* __restrict__ bsum, float* __restrict__ H)
{
  const int c0 = blockIdx.x * 128, b = blockIdx.y, kc = blockIdx.z;
  const int tid = threadIdx.x, lane = tid & 63, w = tid >> 6;
  const int l15 = lane & 15, q = lane >> 4;

  __shared__ __attribute__((aligned(16))) __bf16 At[128*72];  // x tile [c][s]
  __shared__ __attribute__((aligned(16))) __bf16 Bt[128*72];  // attB tile [n][s]
  f32x4 acc[8][2] = {};

  const float* xb = x + ((size_t)b*CIN + c0)*HW;
  const __bf16* ab = BVB + (size_t)b*CN*HW;
  const float* bsb = bsum + b*CN;
  const int colg = tid & 7, row0 = tid >> 3;

  float irow[4];
  #pragma unroll
  for (int p = 0; p < 4; ++p) irow[p] = 1.0f / bsb[row0 + 32*p];

  for (int ki = 0; ki < 7; ++ki) {
    int k0 = kc*448 + ki*64;
    #pragma unroll
    for (int p = 0; p < 4; ++p) {
      int row = row0 + 32*p;
      cvt_store8(&At[row*72 + colg*8], xb + (size_t)row*HW + k0 + colg*8);
    }
    #pragma unroll
    for (int p = 0; p < 4; ++p) {
      int row = row0 + 32*p;
      uint4 rawv = *(const uint4*)(ab + (size_t)row*HW + k0 + colg*8);
      const __bf16* v = (const __bf16*)&rawv;
      __attribute__((aligned(16))) __bf16 t[8];
      #pragma unroll
      for (int j = 0; j < 8; ++j)
        t[j] = (__bf16)(__expf((float)v[j]) * irow[p]);
      *(uint4*)&Bt[row*72 + colg*8] = *(uint4*)t;
    }
    __syncthreads();
    #pragma unroll
    for (int kk = 0; kk < 2; ++kk) {
      short8 a[8], bb[2];
      #pragma unroll
      for (int mi = 0; mi < 8; ++mi)
        a[mi] = *(short8*)&At[(mi*16 + l15)*72 + kk*32 + q*8];
      #pragma unroll
      for (int ni = 0; ni < 2; ++ni)
        bb[ni] = *(short8*)&Bt[(w*32 + ni*16 + l15)*72 + kk*32 + q*8];
      #pragma unroll
      for (int mi = 0; mi < 8; ++mi)
        #pragma unroll
        for (int ni = 0; ni < 2; ++ni)
          acc[mi][ni] = MFMA(a[mi], bb[ni], acc[mi][ni]);
    }
    __syncthreads();
  }

  float* Hb = H + (size_t)b*CIN*CN;
  #pragma unroll
  for (int mi = 0; mi < 8; ++mi)
    #pragma unroll
    for (int ni = 0; ni < 2; ++ni)
      #pragma unroll
      for (int r = 0; r < 4; ++r) {
        int c = c0 + mi*16 + q*4 + r;
        int n = w*32 + ni*16 + l15;
        atomicAdd(&Hb[c*CN + n], acc[mi][ni][r]);
      }
}

// ---------------------------------------------------------------------------
// Kernel 3: G[b] = wA @ H[b] + bA  (M=512 in 64-tiles, N=128, K=512) -> bf16
// wA fp32 converted at staging
// ---------------------------------------------------------------------------
__global__ __launch_bounds__(256) void g_gemm_kernel(
    const float* __restrict__ wA, const float* __restrict__ bA,
    const float* __restrict__ H, __bf16* __restrict__ G)
{
  const int m0 = blockIdx.x * 64, b = blockIdx.y;
  const int tid = threadIdx.x, lane = tid & 63, w = tid >> 6;
  const int l15 = lane & 15, q = lane >> 4;

  __shared__ __attribute__((aligned(16))) __bf16 At[64*72];
  __shared__ __attribute__((aligned(16))) __bf16 Bt[128*72];
  f32x4 acc[4][2] = {};

  const float* Hb = H + (size_t)b*CIN*CN;
  const int colg = tid & 7, row0 = tid >> 3;
  const int nn = tid & 127, gh = tid >> 7;

  for (int k0 = 0; k0 < CIN; k0 += 64) {
    #pragma unroll
    for (int p = 0; p < 2; ++p) {
      int row = row0 + 32*p;
      cvt_store8(&At[row*72 + colg*8], wA + (size_t)(m0+row)*CIN + k0 + colg*8);
    }
    #pragma unroll
    for (int p = 0; p < 4; ++p) {
      int g = gh + 2*p;
      __attribute__((aligned(16))) __bf16 tmp[8];
      #pragma unroll
      for (int j = 0; j < 8; ++j)
        tmp[j] = (__bf16)Hb[(size_t)(k0 + g*8 + j)*CN + nn];
      *(uint4*)&Bt[nn*72 + g*8] = *(uint4*)tmp;
    }
    __syncthreads();
    #pragma unroll
    for (int kk = 0; kk < 2; ++kk) {
      short8 a[4], bb[2];
      #pragma unroll
      for (int mi = 0; mi < 4; ++mi)
        a[mi] = *(short8*)&At[(mi*16 + l15)*72 + kk*32 + q*8];
      #pragma unroll
      for (int ni = 0; ni < 2; ++ni)
        bb[ni] = *(short8*)&Bt[(w*32 + ni*16 + l15)*72 + kk*32 + q*8];
      #pragma unroll
      for (int mi = 0; mi < 4; ++mi)
        #pragma unroll
        for (int ni = 0; ni < 2; ++ni)
          acc[mi][ni] = MFMA(a[mi], bb[ni], acc[mi][ni]);
    }
    __syncthreads();
  }

  #pragma unroll
  for (int mi = 0; mi < 4; ++mi)
    #pragma unroll
    for (int ni = 0; ni < 2; ++ni)
      #pragma unroll
      for (int r = 0; r < 4; ++r) {
        int m = m0 + mi*16 + q*4 + r;
        int n = w*32 + ni*16 + l15;
        G[((size_t)b*CM + m)*CN + n] = (__bf16)(acc[mi][ni][r] + bA[m]);
      }
}

// ---------------------------------------------------------------------------
// Kernel 4: Z[b][m][s] = sum_n G[b][m][n] * attVT[b][s][n]  -> fp32 output
// ---------------------------------------------------------------------------
__global__ __launch_bounds__(256) void z_gemm_kernel(
    const __bf16* __restrict__ G, const __bf16* __restrict__ attVT,
    float* __restrict__ out)
{
  const int m0 = blockIdx.x * 128, s0 = blockIdx.y * 64, b = blockIdx.z;
  const int tid = threadIdx.x, lane = tid & 63, w = tid >> 6;
  const int l15 = lane & 15, q = lane >> 4;

  __shared__ __attribute__((aligned(16))) __bf16 At[128*136];
  __shared__ __attribute__((aligned(16))) __bf16 Bt[64*136];

  const __bf16* Gb = G + ((size_t)b*CM + m0)*CN;
  const __bf16* Vb = attVT + ((size_t)b*HW + s0)*CN;
  const int g = tid & 15, r0 = tid >> 4;
  #pragma unroll
  for (int p = 0; p < 8; ++p) {
    int row = r0 + 16*p;
    *(uint4*)&At[row*136 + g*8] = *(const uint4*)(Gb + (size_t)row*CN + g*8);
  }
  #pragma unroll
  for (int p = 0; p < 4; ++p) {
    int row = r0 + 16*p;
    *(uint4*)&Bt[row*136 + g*8] = *(const uint4*)(Vb + (size_t)row*CN + g*8);
  }
  __syncthreads();

  f32x4 acc[8] = {};
  #pragma unroll
  for (int kk = 0; kk < 4; ++kk) {
    short8 bb = *(short8*)&Bt[(w*16 + l15)*136 + kk*32 + q*8];
    #pragma unroll
    for (int mi = 0; mi < 8; ++mi) {
      short8 a = *(short8*)&At[(mi*16 + l15)*136 + kk*32 + q*8];
      acc[mi] = MFMA(a, bb, acc[mi]);
    }
  }

  const int s = s0 + w*16 + l15;
  #pragma unroll
  for (int mi = 0; mi < 8; ++mi)
    #pragma unroll
    for (int r = 0; r < 4; ++r) {
      int m = m0 + mi*16 + q*4 + r;
      out[((size_t)b*CM + m)*HW + s] = acc[mi][r];
    }
}

// ---------------------------------------------------------------------------
extern "C" void kernel_launch(void* const* d_in, const int* in_sizes, int n_in,
                              void* d_out, int out_size, void* d_ws, size_t ws_size,
                              hipStream_t stream)
{
  (void)in_sizes; (void)n_in; (void)out_size; (void)ws_size;
  const float* x  = (const float*)d_in[0];
  const float* wA = (const float*)d_in[1];
  const float* bA = (const float*)d_in[2];
  const float* wB = (const float*)d_in[3];
  const float* bB = (const float*)d_in[4];
  const float* wV = (const float*)d_in[5];
  const float* bV = (const float*)d_in[6];
  float* out = (float*)d_out;

  char* ws = (char*)d_ws;
  const size_t szBVB   = (size_t)BATCH*CN*HW*2;     // 12,845,056
  const size_t szAttVT = (size_t)BATCH*HW*CN*2;     // 12,845,056
  const size_t szH     = (size_t)BATCH*CIN*CN*4;    //  4,194,304
  const size_t szBsum  = (size_t)BATCH*CN*4;        //      8,192

  char* p = ws;
  __bf16* BVB   = (__bf16*)p; p += szBVB;
  __bf16* attVT = (__bf16*)p; p += szAttVT;
  float*  H     = (float*)p;  p += szH;
  float*  bsum  = (float*)p;  p += szBsum;   // contiguous with H -> one memset
  __bf16* G     = (__bf16*)p;

  hipMemsetAsync(H, 0, szH + szBsum, stream);
  conv_bv_kernel<<<dim3(49,16),   256, 0, stream>>>(x, wB, wV, bB, bV, BVB, attVT, bsum);
  h_gemm_kernel <<<dim3(4,16,7),  256, 0, stream>>>(x, BVB, bsum, H);
  g_gemm_kernel <<<dim3(8,16),    256, 0, stream>>>(wA, bA, H, G);
  z_gemm_kernel <<<dim3(4,49,16), 256, 0, stream>>>(G, attVT, out);
}